// Round 1
// baseline (455.362 us; speedup 1.0000x reference)
//
#include <hip/hip_runtime.h>
#include <hip/hip_bf16.h>

#define B_DIM   16384
#define D_IN    1024
#define D_EXP   1024
#define D_TOW   512
#define N_EXPT  8
#define N_TASK  4

typedef _Float16 f16x8 __attribute__((ext_vector_type(8)));
typedef _Float16 f16x4 __attribute__((ext_vector_type(4)));
typedef float    f32x4 __attribute__((ext_vector_type(4)));

// ---------------- async global->LDS (16B per lane, wave-uniform LDS base) ---
__device__ __forceinline__ void gll16(const void* g, void* l) {
  __builtin_amdgcn_global_load_lds(
      (const __attribute__((address_space(1))) unsigned int*)g,
      (__attribute__((address_space(3))) unsigned int*)l,
      16, 0, 0);
}

// Fragment read from a swizzled [128][64] f16 LDS tile.
// Chunk swizzle: 16B chunk s within a 128B row holds global chunk s^(row&7).
__device__ __forceinline__ f16x8 ldfrag(const _Float16* sM, int rowbase, int ks, int lane) {
  int rl = rowbase + (lane & 15);
  int ch = ((ks << 2) + (lane >> 4)) ^ (rl & 7);
  return *(const f16x8*)&sM[rl * 64 + ch * 8];
}

// ---------------- prep: x -> f16, gates = x @ gate_w (fp32) ----------------
__global__ __launch_bounds__(256) void prep_x_kernel(
    const float* __restrict__ x, const float* __restrict__ gw,
    _Float16* __restrict__ xh, float* __restrict__ gates)
{
  __shared__ float sred[4][8];
  const int t = threadIdx.x;
  const long row = blockIdx.x;
  float4 v = ((const float4*)(x + row * D_IN))[t];
  f16x4 h;
  h[0] = (_Float16)v.x; h[1] = (_Float16)v.y; h[2] = (_Float16)v.z; h[3] = (_Float16)v.w;
  ((f16x4*)(xh + row * D_IN))[t] = h;

  float g[8];
#pragma unroll
  for (int e = 0; e < 8; ++e) g[e] = 0.f;
  const float* wp = gw + (size_t)t * 4 * 8;   // rows t*4..t*4+3 of [1024][8]
  float xs[4] = {v.x, v.y, v.z, v.w};
#pragma unroll
  for (int j = 0; j < 4; ++j)
#pragma unroll
    for (int e = 0; e < 8; ++e) g[e] += xs[j] * wp[j * 8 + e];

#pragma unroll
  for (int e = 0; e < 8; ++e) {
    g[e] += __shfl_xor(g[e], 1);  g[e] += __shfl_xor(g[e], 2);
    g[e] += __shfl_xor(g[e], 4);  g[e] += __shfl_xor(g[e], 8);
    g[e] += __shfl_xor(g[e], 16); g[e] += __shfl_xor(g[e], 32);
  }
  if ((t & 63) == 0) {
#pragma unroll
    for (int e = 0; e < 8; ++e) sred[t >> 6][e] = g[e];
  }
  __syncthreads();
  if (t < 8) gates[row * 8 + t] = sred[0][t] + sred[1][t] + sred[2][t] + sred[3][t];
}

// ---------------- tiled transpose + fp32->f16: in[s][K][N] -> out[s][N][K] --
__global__ __launch_bounds__(256) void transpose_cvt_kernel(
    const float* __restrict__ in, _Float16* __restrict__ outp, int K, int N)
{
  __shared__ float tile[64][65];
  const int t = threadIdx.x;
  const int tx = t & 63, ty = t >> 6;
  const int n0 = blockIdx.x * 64;
  const int k0 = blockIdx.y * 64;
  const long s = blockIdx.z;
  const float* ip = in + s * (long)K * N;
  _Float16* op = outp + s * (long)K * N;
#pragma unroll
  for (int i = 0; i < 16; ++i) {
    int r = ty * 16 + i;
    tile[r][tx] = ip[(long)(k0 + r) * N + n0 + tx];
  }
  __syncthreads();
#pragma unroll
  for (int i = 0; i < 16; ++i) {
    int r = ty * 16 + i;
    op[(long)(n0 + r) * K + k0 + tx] = (_Float16)tile[tx][r];
  }
}

// ---------------- init d_out with tb2 --------------------------------------
__global__ void init_out_kernel(float* __restrict__ out, const float* __restrict__ tb2) {
  int i = blockIdx.x * 256 + threadIdx.x;
  if (i < N_TASK * B_DIM) out[i] = tb2[i >> 14];
}

// ---------------- fused experts + gate-weighted combine ---------------------
// shared[b,d] = sum_e gates[b,e] * relu(x[b,:] @ exp_w[e,:,d] + exp_b[e,d])
__global__ __launch_bounds__(256, 2) void moe_expert_kernel(
    const _Float16* __restrict__ xh,    // [B,1024]
    const _Float16* __restrict__ ewT,   // [8][n=1024][k=1024]
    const float* __restrict__ expb,     // [8][1024]
    const float* __restrict__ gates,    // [B][8]
    _Float16* __restrict__ shout)       // [B,1024] f16
{
  __shared__ alignas(16) _Float16 sA[128 * 64];
  __shared__ alignas(16) _Float16 sB[128 * 64];
  __shared__ float sG[128 * 8];
  const int t = threadIdx.x;
  const int lane = t & 63;
  const int wave = t >> 6;
  const int wm = wave >> 1, wn = wave & 1;
  const long row0 = (long)blockIdx.x * 128;
  const int col0 = blockIdx.y * 128;

#pragma unroll
  for (int i = 0; i < 4; ++i) sG[i * 256 + t] = gates[row0 * 8 + i * 256 + t];

  f32x4 shacc[4][4] = {};

  const char* gA0 = (const char*)(xh + row0 * D_IN);
  for (int e = 0; e < N_EXPT; ++e) {
    const char* gB0 = (const char*)(ewT + (size_t)e * D_IN * D_EXP + (size_t)col0 * D_IN);
    f32x4 acc[4][4] = {};
    for (int k0 = 0; k0 < D_IN; k0 += 64) {
#pragma unroll
      for (int r = 0; r < 4; ++r) {
        int b = r * 4096 + t * 16;       // flat byte in 16KB tile
        int rowl = b >> 7;
        int sl = (b >> 4) & 7;
        int so = ((sl ^ (rowl & 7)) << 4);
        char* ldst = (char*)nullptr;
        ldst = (char*)sA + r * 4096 + ((t >> 6) << 10);
        gll16(gA0 + (size_t)k0 * 2 + (size_t)rowl * 2048 + so, ldst);
        ldst = (char*)sB + r * 4096 + ((t >> 6) << 10);
        gll16(gB0 + (size_t)k0 * 2 + (size_t)rowl * 2048 + so, ldst);
      }
      __syncthreads();
#pragma unroll
      for (int ks = 0; ks < 2; ++ks) {
        f16x8 af[4], bf[4];
#pragma unroll
        for (int m = 0; m < 4; ++m) af[m] = ldfrag(sA, wm * 64 + m * 16, ks, lane);
#pragma unroll
        for (int n = 0; n < 4; ++n) bf[n] = ldfrag(sB, wn * 64 + n * 16, ks, lane);
#pragma unroll
        for (int m = 0; m < 4; ++m)
#pragma unroll
          for (int n = 0; n < 4; ++n)
            acc[m][n] = __builtin_amdgcn_mfma_f32_16x16x32_f16(af[m], bf[n], acc[m][n], 0, 0, 0);
      }
      __syncthreads();
    }
    // epilogue for expert e: relu(acc+bias) weighted by gate, accumulate
#pragma unroll
    for (int n = 0; n < 4; ++n) {
      int col = col0 + wn * 64 + n * 16 + (lane & 15);
      float bias = expb[e * D_EXP + col];
#pragma unroll
      for (int m = 0; m < 4; ++m) {
        int rbase = wm * 64 + m * 16 + ((lane >> 4) << 2);
#pragma unroll
        for (int r = 0; r < 4; ++r) {
          float hv = acc[m][n][r] + bias;
          hv = hv > 0.f ? hv : 0.f;
          shacc[m][n][r] += sG[(rbase + r) * 8 + e] * hv;
        }
      }
    }
  }

  // write shared tile as f16
#pragma unroll
  for (int m = 0; m < 4; ++m)
#pragma unroll
    for (int r = 0; r < 4; ++r) {
      long row = row0 + wm * 64 + m * 16 + ((lane >> 4) << 2) + r;
      _Float16* op = shout + row * D_EXP + col0 + wn * 64 + (lane & 15);
#pragma unroll
      for (int n = 0; n < 4; ++n) op[n * 16] = (_Float16)shacc[m][n][r];
    }
}

// ---------------- fused towers ----------------------------------------------
// out[task,b] += sum_h relu(shared[b,:] @ tw1[task,:,h] + tb1[task,h]) * tw2[task,h]
__global__ __launch_bounds__(256, 2) void moe_tower_kernel(
    const _Float16* __restrict__ sh,    // [B,1024] f16
    const _Float16* __restrict__ t1T,   // [4][h=512][d=1024] f16
    const float* __restrict__ tb1,      // [4][512]
    const float* __restrict__ tw2,      // [4][512]
    float* __restrict__ out)            // [4][B]
{
  __shared__ alignas(16) _Float16 sA[128 * 64];
  __shared__ alignas(16) _Float16 sB[128 * 64];
  const int t = threadIdx.x;
  const int lane = t & 63;
  const int wave = t >> 6;
  const int wm = wave >> 1, wn = wave & 1;
  const long row0 = (long)blockIdx.x * 128;
  const int task = blockIdx.y >> 2;
  const int h0 = (blockIdx.y & 3) * 128;

  const char* gA0 = (const char*)(sh + row0 * D_EXP);
  const char* gB0 = (const char*)(t1T + (size_t)task * D_TOW * D_EXP + (size_t)h0 * D_EXP);

  f32x4 acc[4][4] = {};
  for (int k0 = 0; k0 < D_EXP; k0 += 64) {
#pragma unroll
    for (int r = 0; r < 4; ++r) {
      int b = r * 4096 + t * 16;
      int rowl = b >> 7;
      int sl = (b >> 4) & 7;
      int so = ((sl ^ (rowl & 7)) << 4);
      gll16(gA0 + (size_t)k0 * 2 + (size_t)rowl * 2048 + so,
            (char*)sA + r * 4096 + ((t >> 6) << 10));
      gll16(gB0 + (size_t)k0 * 2 + (size_t)rowl * 2048 + so,
            (char*)sB + r * 4096 + ((t >> 6) << 10));
    }
    __syncthreads();
#pragma unroll
    for (int ks = 0; ks < 2; ++ks) {
      f16x8 af[4], bf[4];
#pragma unroll
      for (int m = 0; m < 4; ++m) af[m] = ldfrag(sA, wm * 64 + m * 16, ks, lane);
#pragma unroll
      for (int n = 0; n < 4; ++n) bf[n] = ldfrag(sB, wn * 64 + n * 16, ks, lane);
#pragma unroll
      for (int m = 0; m < 4; ++m)
#pragma unroll
        for (int n = 0; n < 4; ++n)
          acc[m][n] = __builtin_amdgcn_mfma_f32_16x16x32_f16(af[m], bf[n], acc[m][n], 0, 0, 0);
    }
    __syncthreads();
  }

  float b1[4], w2[4];
#pragma unroll
  for (int n = 0; n < 4; ++n) {
    int col = h0 + wn * 64 + n * 16 + (lane & 15);
    b1[n] = tb1[task * D_TOW + col];
    w2[n] = tw2[task * D_TOW + col];
  }
#pragma unroll
  for (int m = 0; m < 4; ++m)
#pragma unroll
    for (int r = 0; r < 4; ++r) {
      float ssum = 0.f;
#pragma unroll
      for (int n = 0; n < 4; ++n) {
        float v = acc[m][n][r] + b1[n];
        v = v > 0.f ? v : 0.f;
        ssum += v * w2[n];
      }
      // reduce over the 16 lanes of this lane-group (they hold the 64 cols)
      ssum += __shfl_xor(ssum, 1);
      ssum += __shfl_xor(ssum, 2);
      ssum += __shfl_xor(ssum, 4);
      ssum += __shfl_xor(ssum, 8);
      if ((lane & 15) == 0) {
        long row = row0 + wm * 64 + m * 16 + ((lane >> 4) << 2) + r;
        atomicAdd(&out[(size_t)task * B_DIM + row], ssum);
      }
    }
}

// ---------------- launch -----------------------------------------------------
extern "C" void kernel_launch(void* const* d_in, const int* in_sizes, int n_in,
                              void* d_out, int out_size, void* d_ws, size_t ws_size,
                              hipStream_t stream) {
  const float* x    = (const float*)d_in[0];
  const float* gw   = (const float*)d_in[1];
  const float* expw = (const float*)d_in[2];
  const float* expb = (const float*)d_in[3];
  const float* tw1  = (const float*)d_in[4];
  const float* tb1  = (const float*)d_in[5];
  const float* tw2  = (const float*)d_in[6];
  const float* tb2  = (const float*)d_in[7];
  float* out = (float*)d_out;

  char* ws = (char*)d_ws;
  _Float16* xh  = (_Float16*)ws;  ws += (size_t)B_DIM * D_IN * 2;        // 32 MB
  _Float16* ewT = (_Float16*)ws;  ws += (size_t)N_EXPT * D_IN * D_EXP * 2; // 16 MB
  _Float16* t1T = (_Float16*)ws;  ws += (size_t)N_TASK * D_TOW * D_EXP * 2; // 4 MB
  _Float16* shh = (_Float16*)ws;  ws += (size_t)B_DIM * D_EXP * 2;       // 32 MB
  float* gates  = (float*)ws;     ws += (size_t)B_DIM * N_EXPT * 4;      // 0.5 MB

  prep_x_kernel<<<B_DIM, 256, 0, stream>>>(x, gw, xh, gates);
  transpose_cvt_kernel<<<dim3(D_EXP / 64, D_IN / 64, N_EXPT), 256, 0, stream>>>(
      expw, ewT, D_IN, D_EXP);
  transpose_cvt_kernel<<<dim3(D_TOW / 64, D_EXP / 64, N_TASK), 256, 0, stream>>>(
      tw1, t1T, D_EXP, D_TOW);
  init_out_kernel<<<(N_TASK * B_DIM + 255) / 256, 256, 0, stream>>>(out, tb2);
  moe_expert_kernel<<<dim3(B_DIM / 128, D_EXP / 128), 256, 0, stream>>>(
      xh, ewT, expb, gates, shh);
  moe_tower_kernel<<<dim3(B_DIM / 128, (N_TASK * D_TOW) / 128), 256, 0, stream>>>(
      shh, t1T, tb1, tw2, out);
}